// Round 1
// baseline (2152.771 us; speedup 1.0000x reference)
//
#include <hip/hip_runtime.h>
#include <math.h>

#define NN 4
#define FC 32
#define DC 32
#define HH 480
#define WW 640
#define hh 120
#define ww 160
#define RR 20
#define TILE 14
#define ATT 16   // TILE+2 : conv1 output region (att pixels)
#define FT 18    // TILE+4 : feat / pooling region
#define BIAS_IDX 1282  // W//w//2 + (H//h//2)*W = 2 + 2*640

// workspace layout (floats): [0..20) num[r], [20..40) den[r], [64..) w1t (9*32*32), then w2t (9*32*4)
#define WS_W1T 64
#define WS_W2T (WS_W1T + 9*32*32)

__global__ void prep_kernel(const float* __restrict__ W_att, const float* __restrict__ W_post,
                            float* __restrict__ ws) {
    int tid = threadIdx.x;
    if (tid < 2*RR) ws[tid] = 0.f;
    float* w1t = ws + WS_W1T;
    float* w2t = ws + WS_W2T;
    // w1t[tap][c][oc] = W_att[oc][c][tap]   (OIHW input)
    for (int i = tid; i < 32*32*9; i += blockDim.x) {
        int oc = i / (32*9); int rem = i % (32*9); int c = rem / 9; int tap = rem % 9;
        w1t[(tap*32 + c)*32 + oc] = W_att[i];
    }
    // w2t[tap][c][oc2] = W_post[oc2][c][tap]
    for (int i = tid; i < 4*32*9; i += blockDim.x) {
        int oc = i / (32*9); int rem = i % (32*9); int c = rem / 9; int tap = rem % 9;
        w2t[(tap*32 + c)*4 + oc] = W_post[i];
    }
}

__launch_bounds__(256, 2)
__global__ void wvl_main(const float* __restrict__ x, const float* __restrict__ d,
                         const float* __restrict__ gts, const float* __restrict__ rnd,
                         const float* __restrict__ b_att, const float* __restrict__ b_post,
                         float* __restrict__ ws) {
    __shared__ float s_feat[32 * FT * FT];   // [c][pi*18+pj]
    __shared__ float s_attd[32 * ATT * ATT]; // [c][ay*16+ax]
    __shared__ float s_pgt[FT * FT];
    __shared__ int   s_pidx[FT * FT];
    __shared__ float s_rn[4], s_rd[4];

    const float* w1t = ws + WS_W1T;
    const float* w2t = ws + WS_W2T;
    float* numacc = ws;
    float* denacc = ws + RR;

    const int tid = threadIdx.x;
    const int tilesx = (ww + TILE - 1) / TILE;   // 12
    const int tx = blockIdx.x % tilesx;
    const int ty = blockIdx.x / tilesx;
    const int n  = blockIdx.y;
    const int r  = blockIdx.z;

    const int py0 = ty * TILE - 2;   // pooling/feat region origin (18x18)
    const int px0 = tx * TILE - 2;

    // ---------------- Stage 1: random pooling over the 18x18 region ----------------
    const float* gt_n = gts + (size_t)n * HH * WW;
    const float* rd_n = rnd + ((size_t)r * NN + n) * (size_t)(HH * WW);
    for (int p = tid; p < FT * FT; p += 256) {
        int pi = p / FT, pj = p % FT;
        int gi = py0 + pi, gj = px0 + pj;
        float gval = 0.f; int idx = -1;
        if (gi >= 0 && gi < hh && gj >= 0 && gj < ww) {
            float best = -1.f; int bii = 0, bjj = 0; float bg = 0.f;
            #pragma unroll
            for (int bi = 0; bi < 4; ++bi) {
                const float* gr = gt_n + (size_t)(gi*4 + bi) * WW + gj*4;
                const float* rr = rd_n + (size_t)(gi*4 + bi) * WW + gj*4;
                #pragma unroll
                for (int bj = 0; bj < 4; ++bj) {
                    float g  = gr[bj];
                    float rv = rr[bj];
                    float rm = (g > 0.1f) ? rv : 0.f;
                    if (rm > best) { best = rm; bii = bi; bjj = bj; bg = g; }
                }
            }
            gval = bg;
            idx = (gi*4 + bii) * WW + (gj*4 + bjj) + BIAS_IDX;
        }
        s_pgt[p]  = gval;
        s_pidx[p] = idx;
    }
    __syncthreads();

    // ---------------- Stage 2: bilinear grid-sample feat (18x18 x 32c) ----------------
    const float* x_n = x + (size_t)n * FC * HH * WW;
    for (int p = tid; p < FT * FT; p += 256) {
        int idx = s_pidx[p];
        if (idx < 0) {
            for (int c = 0; c < 32; ++c) s_feat[c * (FT*FT) + p] = 0.f;
            continue;
        }
        int cc = idx % WW;
        int rr2 = idx / WW;
        // replicate reference float sequence
        float gxf = 2.0f * ((float)cc  / (float)WW - 0.5f);
        float gyf = 2.0f * ((float)rr2 / (float)HH - 0.5f);
        float ix = (gxf + 1.0f) * 0.5f * (float)(WW - 1);
        float iy = (gyf + 1.0f) * 0.5f * (float)(HH - 1);
        float x0f = floorf(ix), y0f = floorf(iy);
        float wx = ix - x0f, wy = iy - y0f;
        int x0 = (int)x0f, y0 = (int)y0f;
        float vx0 = (x0f >= 0.f        && x0f <= (float)(WW-1)) ? 1.f : 0.f;
        float vx1 = (x0f + 1.f >= 0.f  && x0f + 1.f <= (float)(WW-1)) ? 1.f : 0.f;
        float vy0 = (y0f >= 0.f        && y0f <= (float)(HH-1)) ? 1.f : 0.f;
        float vy1 = (y0f + 1.f >= 0.f  && y0f + 1.f <= (float)(HH-1)) ? 1.f : 0.f;
        int xi0 = min(max(x0, 0), WW-1),  xi1 = min(max(x0+1, 0), WW-1);
        int yi0 = min(max(y0, 0), HH-1),  yi1 = min(max(y0+1, 0), HH-1);
        float w00 = (1.f-wx)*(1.f-wy) * (vx0*vy0);
        float w10 = wx*(1.f-wy)       * (vx1*vy0);
        float w01 = (1.f-wx)*wy       * (vx0*vy1);
        float w11 = wx*wy             * (vx1*vy1);
        const float* p00 = x_n + (size_t)yi0 * WW + xi0;
        const float* p10 = x_n + (size_t)yi0 * WW + xi1;
        const float* p01 = x_n + (size_t)yi1 * WW + xi0;
        const float* p11 = x_n + (size_t)yi1 * WW + xi1;
        #pragma unroll 4
        for (int c = 0; c < 32; ++c) {
            int o = c * (HH * WW);
            float f = w00 * p00[o] + w10 * p10[o] + w01 * p01[o] + w11 * p11[o];
            s_feat[c * (FT*FT) + p] = f;
        }
    }
    __syncthreads();

    // ---------------- Stage 3: conv1 (32->32) + sigmoid + *d ----------------
    // one thread per att pixel (16x16), 32 out channels in registers
    const int ay = tid >> 4, ax = tid & 15;
    float acc[32];
    #pragma unroll
    for (int oc = 0; oc < 32; ++oc) acc[oc] = b_att[oc];

    for (int dy = 0; dy < 3; ++dy) {
        for (int dx = 0; dx < 3; ++dx) {
            const float* wt = w1t + (dy*3 + dx) * 1024;
            int base = (ay + dy) * FT + (ax + dx);
            for (int c = 0; c < 32; ++c) {
                float f = s_feat[c * (FT*FT) + base];
                const float* wp = wt + c * 32;
                #pragma unroll
                for (int oc = 0; oc < 32; ++oc) acc[oc] = fmaf(f, wp[oc], acc[oc]);
            }
        }
    }

    {
        int gy = ty * TILE - 1 + ay;
        int gx = tx * TILE - 1 + ax;
        bool inb = (gy >= 0 && gy < hh && gx >= 0 && gx < ww);
        const float* d_n = d + (size_t)n * DC * hh * ww;
        #pragma unroll
        for (int oc = 0; oc < 32; ++oc) {
            float a = 1.f / (1.f + __expf(-acc[oc]));
            float val = 0.f;
            if (inb) val = a * d_n[(size_t)(oc * hh + gy) * ww + gx];
            s_attd[oc * (ATT*ATT) + tid] = val;
        }
    }
    __syncthreads();

    // ---------------- Stage 4: conv2 (32->4) + log-grad targets + smooth-L1 ----------------
    float num_t = 0.f, den_t = 0.f;
    if (tid < TILE * TILE) {
        int qy = tid / TILE, qx = tid % TILE;
        int gy2 = ty * TILE + qy, gx2 = tx * TILE + qx;
        if (gy2 < hh && gx2 < ww) {
            float acc2[4];
            #pragma unroll
            for (int k = 0; k < 4; ++k) acc2[k] = b_post[k];
            for (int dy = 0; dy < 3; ++dy) {
                for (int dx = 0; dx < 3; ++dx) {
                    const float* wt = w2t + (dy*3 + dx) * 128;
                    int base = (qy + dy) * ATT + (qx + dx);
                    for (int c = 0; c < 32; ++c) {
                        float f = s_attd[c * (ATT*ATT) + base];
                        const float* wp = wt + c * 4;
                        #pragma unroll
                        for (int k = 0; k < 4; ++k) acc2[k] = fmaf(f, wp[k], acc2[k]);
                    }
                }
            }
            // pooling-region coords of this ds pixel: (qy+2, qx+2)
            int pc = (qy + 2) * FT + (qx + 2);
            float rgc = s_pgt[pc]; rgc = (rgc < 0.1f) ? 0.f : rgc;
            float lc = logf(rgc + 1e-6f);
            bool  mc = rgc > 0.1f;
            const int oys[4] = {0, 1, 1, 1};
            const int oxs[4] = {1, 1, 0, -1};
            #pragma unroll
            for (int k = 0; k < 4; ++k) {
                int pnb = (qy + 2 + oys[k]) * FT + (qx + 2 + oxs[k]);
                float rgn = s_pgt[pnb]; rgn = (rgn < 0.1f) ? 0.f : rgn;
                float ln = logf(rgn + 1e-6f);
                bool m = mc && (rgn > 0.1f);
                float gg = lc - ln;
                float a2 = fabsf(acc2[k] - gg);
                float sl1 = (a2 < 0.01f) ? (0.5f * a2 * a2 / 0.01f) : (a2 - 0.005f);
                if (m) { num_t += sl1; den_t += 1.f; }
            }
        }
    }

    // block reduction
    for (int off = 32; off > 0; off >>= 1) {
        num_t += __shfl_down(num_t, off);
        den_t += __shfl_down(den_t, off);
    }
    int wid = tid >> 6, lane = tid & 63;
    if (lane == 0) { s_rn[wid] = num_t; s_rd[wid] = den_t; }
    __syncthreads();
    if (tid == 0) {
        float tn = s_rn[0] + s_rn[1] + s_rn[2] + s_rn[3];
        float td = s_rd[0] + s_rd[1] + s_rd[2] + s_rd[3];
        atomicAdd(&numacc[r], tn);
        atomicAdd(&denacc[r], td);
    }
}

__global__ void finish_kernel(const float* __restrict__ ws, float* __restrict__ out) {
    if (threadIdx.x == 0 && blockIdx.x == 0) {
        float s = 0.f;
        for (int r = 0; r < RR; ++r) s += ws[r] / ws[RR + r];
        out[0] = s / (float)RR;
    }
}

extern "C" void kernel_launch(void* const* d_in, const int* in_sizes, int n_in,
                              void* d_out, int out_size, void* d_ws, size_t ws_size,
                              hipStream_t stream) {
    const float* x      = (const float*)d_in[0];
    const float* d      = (const float*)d_in[1];
    const float* gts    = (const float*)d_in[2];
    const float* rnd    = (const float*)d_in[3];
    const float* W_att  = (const float*)d_in[4];
    const float* b_att  = (const float*)d_in[5];
    const float* W_post = (const float*)d_in[6];
    const float* b_post = (const float*)d_in[7];
    float* out = (float*)d_out;
    float* ws  = (float*)d_ws;

    hipLaunchKernelGGL(prep_kernel, dim3(1), dim3(1024), 0, stream, W_att, W_post, ws);

    const int tilesx = (ww + TILE - 1) / TILE;  // 12
    const int tilesy = (hh + TILE - 1) / TILE;  // 9
    dim3 grid(tilesx * tilesy, NN, RR);
    hipLaunchKernelGGL(wvl_main, grid, dim3(256), 0, stream,
                       x, d, gts, rnd, b_att, b_post, ws);

    hipLaunchKernelGGL(finish_kernel, dim3(1), dim3(64), 0, stream, ws, out);
}

// Round 2
// 1535.365 us; speedup vs baseline: 1.4021x; 1.4021x over previous
//
#include <hip/hip_runtime.h>
#include <math.h>

#define NN 4
#define FC 32
#define DC 32
#define HH 480
#define WW 640
#define hh 120
#define ww 160
#define RR 20
#define TILE 14
#define ATT 16   // TILE+2 : conv1 output region (att pixels)
#define FT 18    // TILE+4 : feat / pooling region
#define BIAS_IDX 1282  // W//w//2 + (H//h//2)*W = 2 + 2*640
#define CP 16    // channel pairs (32 channels / 2)

// workspace layout (floats): [0..20) num[r], [20..40) den[r], [64..) w1t (9*32*32), then w2t (9*32*4)
#define WS_W1T 64
#define WS_W2T (WS_W1T + 9*32*32)

__device__ __forceinline__ unsigned int bf16pack(float a, float b) {
    unsigned int ua = __float_as_uint(a);
    ua = (ua + 0x7fffu + ((ua >> 16) & 1u)) >> 16;
    unsigned int ub = __float_as_uint(b);
    ub = (ub + 0x7fffu + ((ub >> 16) & 1u)) >> 16;
    return ua | (ub << 16);
}

__global__ void prep_kernel(const float* __restrict__ W_att, const float* __restrict__ W_post,
                            float* __restrict__ ws) {
    int tid = threadIdx.x;
    if (tid < 2*RR) ws[tid] = 0.f;
    float* w1t = ws + WS_W1T;
    float* w2t = ws + WS_W2T;
    // w1t[tap][c][oc] = W_att[oc][c][tap]   (OIHW input)
    for (int i = tid; i < 32*32*9; i += blockDim.x) {
        int oc = i / (32*9); int rem = i % (32*9); int c = rem / 9; int tap = rem % 9;
        w1t[(tap*32 + c)*32 + oc] = W_att[i];
    }
    // w2t[tap][c][oc2] = W_post[oc2][c][tap]
    for (int i = tid; i < 4*32*9; i += blockDim.x) {
        int oc = i / (32*9); int rem = i % (32*9); int c = rem / 9; int tap = rem % 9;
        w2t[(tap*32 + c)*4 + oc] = W_post[i];
    }
}

__launch_bounds__(256, 6)
__global__ void wvl_main(const float* __restrict__ x, const float* __restrict__ d,
                         const float* __restrict__ gts, const float* __restrict__ rnd,
                         const float* __restrict__ b_att, const float* __restrict__ b_post,
                         float* __restrict__ ws) {
    // bf16 channel-pair packed buffer. Phase A: feat [cp][FT*FT] (16*324 dwords).
    // Phase B (after barrier, reuses same memory): att*d [cp][ATT*ATT] (16*256 dwords).
    __shared__ unsigned int s_buf[CP * FT * FT];
    __shared__ float s_pgt[FT * FT];
    __shared__ int   s_pidx[FT * FT];
    __shared__ float s_rn[4], s_rd[4];

    const float* w1t = ws + WS_W1T;
    const float* w2t = ws + WS_W2T;
    float* numacc = ws;
    float* denacc = ws + RR;

    const int tid = threadIdx.x;
    const int tilesx = (ww + TILE - 1) / TILE;   // 12
    const int tx = blockIdx.x % tilesx;
    const int ty = blockIdx.x / tilesx;
    const int n  = blockIdx.y;
    const int r  = blockIdx.z;

    const int py0 = ty * TILE - 2;   // pooling/feat region origin (18x18)
    const int px0 = tx * TILE - 2;

    // ---------------- Stage 1: random pooling over the 18x18 region ----------------
    const float* gt_n = gts + (size_t)n * HH * WW;
    const float* rd_n = rnd + ((size_t)r * NN + n) * (size_t)(HH * WW);
    for (int p = tid; p < FT * FT; p += 256) {
        int pi = p / FT, pj = p % FT;
        int gi = py0 + pi, gj = px0 + pj;
        float gval = 0.f; int idx = -1;
        if (gi >= 0 && gi < hh && gj >= 0 && gj < ww) {
            float best = -1.f; int bii = 0, bjj = 0; float bg = 0.f;
            #pragma unroll
            for (int bi = 0; bi < 4; ++bi) {
                const float* gr = gt_n + (size_t)(gi*4 + bi) * WW + gj*4;
                const float* rr = rd_n + (size_t)(gi*4 + bi) * WW + gj*4;
                #pragma unroll
                for (int bj = 0; bj < 4; ++bj) {
                    float g  = gr[bj];
                    float rv = rr[bj];
                    float rm = (g > 0.1f) ? rv : 0.f;
                    if (rm > best) { best = rm; bii = bi; bjj = bj; bg = g; }
                }
            }
            gval = bg;
            idx = (gi*4 + bii) * WW + (gj*4 + bjj) + BIAS_IDX;
        }
        s_pgt[p]  = gval;
        s_pidx[p] = idx;
    }
    __syncthreads();

    // ---------------- Stage 2: bilinear grid-sample feat (18x18 x 32c, bf16-pair) ----------------
    const float* x_n = x + (size_t)n * FC * HH * WW;
    for (int p = tid; p < FT * FT; p += 256) {
        int idx = s_pidx[p];
        if (idx < 0) {
            #pragma unroll
            for (int cp = 0; cp < CP; ++cp) s_buf[cp * (FT*FT) + p] = 0u;
            continue;
        }
        int cc = idx % WW;
        int rr2 = idx / WW;
        // replicate reference float sequence
        float gxf = 2.0f * ((float)cc  / (float)WW - 0.5f);
        float gyf = 2.0f * ((float)rr2 / (float)HH - 0.5f);
        float ix = (gxf + 1.0f) * 0.5f * (float)(WW - 1);
        float iy = (gyf + 1.0f) * 0.5f * (float)(HH - 1);
        float x0f = floorf(ix), y0f = floorf(iy);
        float wx = ix - x0f, wy = iy - y0f;
        int x0 = (int)x0f, y0 = (int)y0f;
        float vx0 = (x0f >= 0.f        && x0f <= (float)(WW-1)) ? 1.f : 0.f;
        float vx1 = (x0f + 1.f >= 0.f  && x0f + 1.f <= (float)(WW-1)) ? 1.f : 0.f;
        float vy0 = (y0f >= 0.f        && y0f <= (float)(HH-1)) ? 1.f : 0.f;
        float vy1 = (y0f + 1.f >= 0.f  && y0f + 1.f <= (float)(HH-1)) ? 1.f : 0.f;
        int xi0 = min(max(x0, 0), WW-1),  xi1 = min(max(x0+1, 0), WW-1);
        int yi0 = min(max(y0, 0), HH-1),  yi1 = min(max(y0+1, 0), HH-1);
        float w00 = (1.f-wx)*(1.f-wy) * (vx0*vy0);
        float w10 = wx*(1.f-wy)       * (vx1*vy0);
        float w01 = (1.f-wx)*wy       * (vx0*vy1);
        float w11 = wx*wy             * (vx1*vy1);
        const float* p00 = x_n + (size_t)yi0 * WW + xi0;
        const float* p10 = x_n + (size_t)yi0 * WW + xi1;
        const float* p01 = x_n + (size_t)yi1 * WW + xi0;
        const float* p11 = x_n + (size_t)yi1 * WW + xi1;
        #pragma unroll 4
        for (int cp = 0; cp < CP; ++cp) {
            int o0 = (2*cp)     * (HH * WW);
            int o1 = (2*cp + 1) * (HH * WW);
            float f0 = w00 * p00[o0] + w10 * p10[o0] + w01 * p01[o0] + w11 * p11[o0];
            float f1 = w00 * p00[o1] + w10 * p10[o1] + w01 * p01[o1] + w11 * p11[o1];
            s_buf[cp * (FT*FT) + p] = bf16pack(f0, f1);
        }
    }
    __syncthreads();

    // ---------------- Stage 3: conv1 (32->32) + sigmoid + *d ----------------
    // one thread per att pixel (16x16), 32 out channels in registers
    const int ay = tid >> 4, ax = tid & 15;
    float acc[32];
    #pragma unroll
    for (int oc = 0; oc < 32; ++oc) acc[oc] = b_att[oc];

    for (int dy = 0; dy < 3; ++dy) {
        for (int dx = 0; dx < 3; ++dx) {
            const float* wt = w1t + (dy*3 + dx) * 1024;
            int base = (ay + dy) * FT + (ax + dx);
            for (int cp = 0; cp < CP; ++cp) {
                unsigned int u = s_buf[cp * (FT*FT) + base];
                float f0 = __uint_as_float(u << 16);
                float f1 = __uint_as_float(u & 0xffff0000u);
                const float* wp0 = wt + (2*cp) * 32;
                const float* wp1 = wp0 + 32;
                #pragma unroll
                for (int oc = 0; oc < 32; ++oc) acc[oc] = fmaf(f0, wp0[oc], acc[oc]);
                #pragma unroll
                for (int oc = 0; oc < 32; ++oc) acc[oc] = fmaf(f1, wp1[oc], acc[oc]);
            }
        }
    }

    // all reads of feat done -> safe to repurpose s_buf for att*d after barrier
    __syncthreads();

    {
        int gy = ty * TILE - 1 + ay;
        int gx = tx * TILE - 1 + ax;
        bool inb = (gy >= 0 && gy < hh && gx >= 0 && gx < ww);
        const float* d_n = d + (size_t)n * DC * hh * ww;
        #pragma unroll
        for (int cp = 0; cp < CP; ++cp) {
            float a0 = 1.f / (1.f + __expf(-acc[2*cp]));
            float a1 = 1.f / (1.f + __expf(-acc[2*cp+1]));
            float v0 = 0.f, v1 = 0.f;
            if (inb) {
                v0 = a0 * d_n[(size_t)((2*cp)   * hh + gy) * ww + gx];
                v1 = a1 * d_n[(size_t)((2*cp+1) * hh + gy) * ww + gx];
            }
            s_buf[cp * (ATT*ATT) + tid] = bf16pack(v0, v1);
        }
    }
    __syncthreads();

    // ---------------- Stage 4: conv2 (32->4) + log-grad targets + smooth-L1 ----------------
    float num_t = 0.f, den_t = 0.f;
    if (tid < TILE * TILE) {
        int qy = tid / TILE, qx = tid % TILE;
        int gy2 = ty * TILE + qy, gx2 = tx * TILE + qx;
        if (gy2 < hh && gx2 < ww) {
            float acc2[4];
            #pragma unroll
            for (int k = 0; k < 4; ++k) acc2[k] = b_post[k];
            for (int dy = 0; dy < 3; ++dy) {
                for (int dx = 0; dx < 3; ++dx) {
                    const float* wt = w2t + (dy*3 + dx) * 128;
                    int base = (qy + dy) * ATT + (qx + dx);
                    for (int cp = 0; cp < CP; ++cp) {
                        unsigned int u = s_buf[cp * (ATT*ATT) + base];
                        float f0 = __uint_as_float(u << 16);
                        float f1 = __uint_as_float(u & 0xffff0000u);
                        const float* wp0 = wt + (2*cp) * 4;
                        const float* wp1 = wp0 + 4;
                        #pragma unroll
                        for (int k = 0; k < 4; ++k) acc2[k] = fmaf(f0, wp0[k], acc2[k]);
                        #pragma unroll
                        for (int k = 0; k < 4; ++k) acc2[k] = fmaf(f1, wp1[k], acc2[k]);
                    }
                }
            }
            // pooling-region coords of this ds pixel: (qy+2, qx+2)
            int pc = (qy + 2) * FT + (qx + 2);
            float rgc = s_pgt[pc]; rgc = (rgc < 0.1f) ? 0.f : rgc;
            float lc = logf(rgc + 1e-6f);
            bool  mc = rgc > 0.1f;
            const int oys[4] = {0, 1, 1, 1};
            const int oxs[4] = {1, 1, 0, -1};
            #pragma unroll
            for (int k = 0; k < 4; ++k) {
                int pnb = (qy + 2 + oys[k]) * FT + (qx + 2 + oxs[k]);
                float rgn = s_pgt[pnb]; rgn = (rgn < 0.1f) ? 0.f : rgn;
                float ln = logf(rgn + 1e-6f);
                bool m = mc && (rgn > 0.1f);
                float gg = lc - ln;
                float a2 = fabsf(acc2[k] - gg);
                float sl1 = (a2 < 0.01f) ? (0.5f * a2 * a2 / 0.01f) : (a2 - 0.005f);
                if (m) { num_t += sl1; den_t += 1.f; }
            }
        }
    }

    // block reduction
    for (int off = 32; off > 0; off >>= 1) {
        num_t += __shfl_down(num_t, off);
        den_t += __shfl_down(den_t, off);
    }
    int wid = tid >> 6, lane = tid & 63;
    if (lane == 0) { s_rn[wid] = num_t; s_rd[wid] = den_t; }
    __syncthreads();
    if (tid == 0) {
        float tn = s_rn[0] + s_rn[1] + s_rn[2] + s_rn[3];
        float td = s_rd[0] + s_rd[1] + s_rd[2] + s_rd[3];
        atomicAdd(&numacc[r], tn);
        atomicAdd(&denacc[r], td);
    }
}

__global__ void finish_kernel(const float* __restrict__ ws, float* __restrict__ out) {
    if (threadIdx.x == 0 && blockIdx.x == 0) {
        float s = 0.f;
        for (int r = 0; r < RR; ++r) s += ws[r] / ws[RR + r];
        out[0] = s / (float)RR;
    }
}

extern "C" void kernel_launch(void* const* d_in, const int* in_sizes, int n_in,
                              void* d_out, int out_size, void* d_ws, size_t ws_size,
                              hipStream_t stream) {
    const float* x      = (const float*)d_in[0];
    const float* d      = (const float*)d_in[1];
    const float* gts    = (const float*)d_in[2];
    const float* rnd    = (const float*)d_in[3];
    const float* W_att  = (const float*)d_in[4];
    const float* b_att  = (const float*)d_in[5];
    const float* W_post = (const float*)d_in[6];
    const float* b_post = (const float*)d_in[7];
    float* out = (float*)d_out;
    float* ws  = (float*)d_ws;

    hipLaunchKernelGGL(prep_kernel, dim3(1), dim3(1024), 0, stream, W_att, W_post, ws);

    const int tilesx = (ww + TILE - 1) / TILE;  // 12
    const int tilesy = (hh + TILE - 1) / TILE;  // 9
    dim3 grid(tilesx * tilesy, NN, RR);
    hipLaunchKernelGGL(wvl_main, grid, dim3(256), 0, stream,
                       x, d, gts, rnd, b_att, b_post, ws);

    hipLaunchKernelGGL(finish_kernel, dim3(1), dim3(64), 0, stream, ws, out);
}